// Round 6
// baseline (162.050 us; speedup 1.0000x reference)
//
#include <hip/hip_runtime.h>
#include <hip/hip_bf16.h>
#include <math.h>

// TriangleAttention — round 12: round-7 ring structure resurrected (37.1 KB LDS
// -> 4 blocks/CU) with both round-7/8 killers removed:
//   * __launch_bounds__(256,3) NOT (256,4): the (256,4) clamp forced 64 VGPRs
//     and spilled ~700 MB. With ~116 VGPRs <= 128 the HW still co-schedules
//     4 blocks/CU (LDS 37376 B); the bound only sets the allocator's floor.
//   * exp/rcp via single-instruction inline asm (round-11-validated), never
//     reading an MFMA destination directly — a compiler-generated VALU op
//     (s[i]*L2E mul / gate add) absorbs the MFMA->VALU hazard wait-states.
// BAN LIST (rounds 7-8): __builtin_amdgcn_exp2f / __builtin_amdgcn_rcpf ->
// phantom scratch traffic. CANARY: WRITE_SIZE ~16.4 MB, FETCH ~66 MB,
// VGPR <= 128.
// B=2, L=256, D=64, H=4, Dh=16.
// ka: grid 2048=(bl,h), 4 waves; wave w owns queries [w*64, w*64+64).
//     S^T = K@Q^T so P-lanes hold 4 consecutive j -> packed b64 P stores;
//     PV as O^T = V^T @ P^T; O^T/G^T layouts match -> coalesced GO stores.
//     znl staged through a 2-slot ring (rows for tiles 2,3 held packed in
//     registers until slots free; DS ops are in-order per wave). Q^T uses a
//     single 256-sh slot, qa[t] read back immediately per tile. P^T overlays
//     the dead ring+QT space after the barrier.
// k3: out = sum_h GO_h @ Wo_h^T + bo (grid 1024); operand-swapped MFMA ->
//     transposed C fragment -> f32x4 vectorized stores.
//
// mfma_f32_16x16x32_bf16 layouts (verified rounds 2-5):
//   A[m = lane&15][k = quad*8 + u]
//   B[k = quad*8 + u][n = lane&15]
//   C/D: col = lane&15, row = quad*4 + reg

typedef __attribute__((ext_vector_type(4))) float f32x4;
typedef __attribute__((ext_vector_type(8))) short s16x8;

#define MFMA16(a, b, c) __builtin_amdgcn_mfma_f32_16x16x32_bf16((a), (b), (c), 0, 0, 0)

__device__ __forceinline__ float exp2a(float x) {   // raw v_exp_f32 (input MUST
    float r;                                        // be VALU-produced, not MFMA)
    asm("v_exp_f32 %0, %1" : "=v"(r) : "v"(x));
    return r;
}
__device__ __forceinline__ float rcpa(float x) {    // raw v_rcp_f32 (same rule)
    float r;
    asm("v_rcp_f32 %0, %1" : "=v"(r) : "v"(x));
    return r;
}

__device__ __forceinline__ unsigned pk2(float a, float b) {   // 2xf32 -> packed bf16x2 (RNE)
    union { __hip_bfloat162 h; unsigned u; } c;
    float2 t; t.x = a; t.y = b;
    c.h = __float22bfloat162_rn(t);
    return c.u;
}
__device__ __forceinline__ s16x8 cvt8(const float* p) {  // 8 fp32 -> bf16x8
    union { unsigned u[4]; s16x8 v; } r;
    r.u[0] = pk2(p[0], p[1]); r.u[1] = pk2(p[2], p[3]);
    r.u[2] = pk2(p[4], p[5]); r.u[3] = pk2(p[6], p[7]);
    return r.v;
}

// LDS map (shorts). Per-wave slice (2560 sh) at wsl = w*2560:
//   phase 1: ring slot s at [s*1024, +1024) (s=0,1); QT slot at [2048, +256)
//   phase 2: P^T(qt) at [qt*640, +640) (stride 40/row) — overlays ring+QT.
// Shared: KSH [256 pos][16 dh], VT [16 dh][264 pos-padded].
static constexpr int WSLICE = 2560;
static constexpr int ZNL = 0;          // 4 * 2560 = 10240 sh
static constexpr int KSH = 10240;      // 4096 sh
static constexpr int VT  = 14336;      // 4224 sh
static constexpr int LDS_EL = 18560;   // 37120 B -> 4 blocks/CU

__global__ __launch_bounds__(256, 3)
void ka_fused(const float* __restrict__ z, const float* __restrict__ ln_s,
              const float* __restrict__ ln_b, const float* __restrict__ Wq,
              const float* __restrict__ Wk, const float* __restrict__ Wv,
              const float* __restrict__ Wg, const float* __restrict__ bg,
              short* __restrict__ ws)
{
    __shared__ __align__(16) short lds[LDS_EL];
    const int tid = threadIdx.x, lane = tid & 63, w = tid >> 6;
    const int n16 = lane & 15, quad = lane >> 4;
    const bool qlo = (quad < 2);
    const int g = blockIdx.x, bl = g >> 2, h = g & 3;
    const size_t rowbase = (size_t)bl * (256 * 64);
    const int wsl = w * WSLICE;                    // wave's scratch slice

    // ---- LN: thread = position tid; pack row to bf16 in registers ----
    union { unsigned u[32]; s16x8 v8[8]; } row;
    {
        float zn[64];
        const float4* zp4 = (const float4*)(z + rowbase + (size_t)tid * 64);
        #pragma unroll
        for (int gq = 0; gq < 16; ++gq) {
            float4 v4 = zp4[gq];
            zn[gq * 4 + 0] = v4.x; zn[gq * 4 + 1] = v4.y;
            zn[gq * 4 + 2] = v4.z; zn[gq * 4 + 3] = v4.w;
        }
        float mu = 0.f;
        #pragma unroll
        for (int k = 0; k < 64; ++k) mu += zn[k];
        mu *= (1.f / 64.f);
        float va = 0.f;
        #pragma unroll
        for (int k = 0; k < 64; ++k) { float d = zn[k] - mu; va += d * d; }
        const float rs = rsqrtf(va * (1.f / 64.f) + 1e-5f);
        #pragma unroll
        for (int k = 0; k < 64; ++k) zn[k] = (zn[k] - mu) * rs * ln_s[k] + ln_b[k];
        #pragma unroll
        for (int k = 0; k < 32; ++k) row.u[k] = pk2(zn[2 * k], zn[2 * k + 1]);
    }

    auto store_row = [&](int slot) {               // swizzled row store into ring
        #pragma unroll
        for (int gq = 0; gq < 8; ++gq)
            *(s16x8*)&lds[ZNL + wsl + slot * 1024 + (lane & 15) * 64
                          + ((gq ^ (lane & 7)) * 8)] = row.v8[gq];
    };

    // ---- W head-slice frags (serve as A for Q/K/G-transposed, B for V) ----
    s16x8 bq[2], bk[2], bv[2], bgf[2];
    #pragma unroll
    for (int ks = 0; ks < 2; ++ks) {
        size_t off = (size_t)(h * 16 + n16) * 64 + ks * 32 + quad * 8;
        bq[ks] = cvt8(Wq + off);  bk[ks] = cvt8(Wk + off);
        bv[ks] = cvt8(Wv + off);  bgf[ks] = cvt8(Wg + off);
    }
    const float4 bg4 = *(const float4*)(bg + h * 16 + quad * 4);
    constexpr float QS  = 0.25f;                            // 1/sqrt(Dh); log2e at exp
    constexpr float L2E = 1.44269504088896340736f;

    float g4t[4][4];
    s16x8 qa[4];
    auto proj_tile = [&](int t, int s) {           // projections for tile t from ring slot s
        s16x8 zn0 = *(const s16x8*)&lds[ZNL + wsl + s * 1024 + n16 * 64
                                        + ((quad ^ (n16 & 7)) * 8)];
        s16x8 zn1 = *(const s16x8*)&lds[ZNL + wsl + s * 1024 + n16 * 64
                                        + (((4 + quad) ^ (n16 & 7)) * 8)];
        f32x4 aq = {}, ak = {}, av = {}, ag = {};
        aq = MFMA16(bq[0], zn0, aq);  aq = MFMA16(bq[1], zn1, aq);   // Q^T
        ak = MFMA16(bk[0], zn0, ak);  ak = MFMA16(bk[1], zn1, ak);   // K^T
        ag = MFMA16(bgf[0], zn0, ag); ag = MFMA16(bgf[1], zn1, ag);  // G^T
        av = MFMA16(zn0, bv[0], av);  av = MFMA16(zn1, bv[1], av);   // V
        {   // Q^T (scaled) -> single QT slot
            uint2 p = {pk2(aq[0] * QS, aq[1] * QS), pk2(aq[2] * QS, aq[3] * QS)};
            *(uint2*)&lds[ZNL + wsl + 2048 + n16 * 16 + quad * 4] = p;
        }
        {   // K^T -> KSH[pos][dh] (shared)
            uint2 p = {pk2(ak[0], ak[1]), pk2(ak[2], ak[3])};
            *(uint2*)&lds[KSH + (w * 64 + t * 16 + n16) * 16 + quad * 4] = p;
        }
        {   // V -> VT[dh][pos] (shared)
            uint2 p = {pk2(av[0], av[1]), pk2(av[2], av[3])};
            *(uint2*)&lds[VT + n16 * 264 + (w * 64 + t * 16 + quad * 4)] = p;
        }
        #pragma unroll
        for (int r = 0; r < 4; ++r)                 // gate (pos=n16, dh=q*4+r)
            g4t[t][r] = rcpa(1.f + __expf(-(ag[r] + bg4[r])));   // add absorbs hazard
        // Q^T B-frag for this tile, read back immediately (slot reused next tile;
        // DS ops are in-order within the wave). Quads 2,3 zero: Dh=16 < K=32.
        s16x8 q = {};
        if (qlo) q = *(const s16x8*)&lds[ZNL + wsl + 2048 + n16 * 16 + quad * 8];
        qa[t] = q;
    };

    // 2-deep staging ring: tiles 0,1 stored now; 2,3 held in regs until free.
    if (lane < 32) store_row(lane >> 4);           // tiles 0,1 -> slots 0,1
    proj_tile(0, 0);
    if (lane >= 32 && lane < 48) store_row(0);     // tile 2 -> slot 0
    proj_tile(1, 1);
    if (lane >= 48) store_row(1);                  // tile 3 -> slot 1
    proj_tile(2, 0);
    proj_tile(3, 1);
    __syncthreads();   // the ONLY barrier: KSH/VT visible

    // ---- attention: S^T = K@Q^T, P^T packed to LDS, O^T = V^T@P^T ----
    float lrow[4][4];
    f32x4 o4[4];
    #pragma unroll
    for (int qt = 0; qt < 4; ++qt) {
        o4[qt] = {};
        #pragma unroll
        for (int r = 0; r < 4; ++r) lrow[qt][r] = 0.f;
    }
    const int sw = (n16 ^ (n16 >> 2)) & 3;          // octet swizzle for P^T
    for (int ch = 0; ch < 8; ++ch) {                // 32 keys per chunk
        #pragma unroll
        for (int jtl = 0; jtl < 2; ++jtl) {
            int jt = ch * 2 + jtl;
            s16x8 kf = {};
            if (qlo) kf = *(const s16x8*)&lds[KSH + (jt * 16 + n16) * 16 + quad * 8];
            const int po = (((jtl * 2 + (quad >> 1)) ^ sw) * 8) + (quad & 1) * 4;
            #pragma unroll
            for (int qt = 0; qt < 4; ++qt) {
                f32x4 zc = {};
                f32x4 s = MFMA16(kf, qa[qt], zc);   // S^T tile: col=i, row=j
                // v_mul (compiler VALU) absorbs the MFMA->read hazard, then the
                // asm v_exp reads a VALU result (hardware-interlocked).
                float e0 = exp2a(s[0] * L2E), e1 = exp2a(s[1] * L2E);
                float e2 = exp2a(s[2] * L2E), e3 = exp2a(s[3] * L2E);
                lrow[qt][0] += e0; lrow[qt][1] += e1;
                lrow[qt][2] += e2; lrow[qt][3] += e3;
                uint2 p = {pk2(e0, e1), pk2(e2, e3)};
                *(uint2*)&lds[ZNL + wsl + qt * 640 + n16 * 40 + po] = p;
            }
        }
        s16x8 vf = *(const s16x8*)&lds[VT + n16 * 264 + ch * 32 + quad * 8];
        #pragma unroll
        for (int qt = 0; qt < 4; ++qt) {
            s16x8 pf = *(const s16x8*)&lds[ZNL + wsl + qt * 640 + n16 * 40
                                           + ((quad ^ sw) * 8)];
            o4[qt] = MFMA16(vf, pf, o4[qt]);        // O^T: col=i, row=dh
        }
    }

    // ---- epilogue: l-reduce, gate, direct coalesced GO stores ----
    #pragma unroll
    for (int qt = 0; qt < 4; ++qt) {
        float l = lrow[qt][0] + lrow[qt][1] + lrow[qt][2] + lrow[qt][3];
        l += __shfl_xor(l, 16);
        l += __shfl_xor(l, 32);
        const float inv = rcpa(l);                  // l is VALU-produced: safe
        float g0 = g4t[qt][0] * o4[qt][0] * inv;
        float g1 = g4t[qt][1] * o4[qt][1] * inv;
        float g2 = g4t[qt][2] * o4[qt][2] * inv;
        float g3 = g4t[qt][3] * o4[qt][3] * inv;
        uint2 p = {pk2(g0, g1), pk2(g2, g3)};
        short* dst = ws + (((size_t)h * 512 + bl) * 256 + w * 64 + qt * 16 + n16) * 16
                     + quad * 4;
        *(uint2*)dst = p;
    }
}

// ---------------------------------------------------------------- kernel 3
// out = sum_h GO_h @ Wo_h^T + bo ; grid 1024 (bl,half), block 256, 32 rows/wave.
// Operand-swapped MFMA -> D col(lane&15) = row, D row(quad*4+r) = 4 consecutive
// out cols -> f32x4 stores.
__global__ __launch_bounds__(256, 4)
void k3_out(const short* __restrict__ ws, const float* __restrict__ Wo,
            const float* __restrict__ bo, float* __restrict__ out)
{
    const int tid = threadIdx.x, lane = tid & 63, w = tid >> 6;
    const int n16 = lane & 15, quad = lane >> 4;
    const short* GO = ws;
    const int bl = blockIdx.x >> 1, half = blockIdx.x & 1;
    const int rowloc = half * 128 + w * 32;

    s16x8 bfr[4][2];   // Wo[outd = nt*16+n16][ind = c*32 + quad*8 + u]
    #pragma unroll
    for (int nt = 0; nt < 4; ++nt)
        #pragma unroll
        for (int ks = 0; ks < 2; ++ks)
            bfr[nt][ks] = cvt8(Wo + (size_t)(nt * 16 + n16) * 64 + ks * 32 + quad * 8);

    f32x4 acc[2][4] = {};
    #pragma unroll
    for (int mt = 0; mt < 2; ++mt) {
        #pragma unroll
        for (int c = 0; c < 2; ++c) {
            int hp = c * 2 + (quad >> 1);
            const short* ap = &GO[(((size_t)hp * 512 + bl) * 256 + rowloc + mt * 16 + n16) * 16
                                  + (quad & 1) * 8];
            s16x8 a = *(const s16x8*)ap;
            #pragma unroll
            for (int nt = 0; nt < 4; ++nt)
                acc[mt][nt] = MFMA16(bfr[nt][c], a, acc[mt][nt]);   // swapped
        }
    }
    #pragma unroll
    for (int nt = 0; nt < 4; ++nt) {
        const float4 b4 = *(const float4*)(bo + nt * 16 + quad * 4);
        f32x4 b4v; b4v[0] = b4.x; b4v[1] = b4.y; b4v[2] = b4.z; b4v[3] = b4.w;
        #pragma unroll
        for (int mt = 0; mt < 2; ++mt) {
            f32x4 v = acc[mt][nt] + b4v;
            *(f32x4*)&out[((size_t)bl * 256 + rowloc + mt * 16 + n16) * 64
                          + nt * 16 + quad * 4] = v;
        }
    }
}

extern "C" void kernel_launch(void* const* d_in, const int* in_sizes, int n_in,
                              void* d_out, int out_size, void* d_ws, size_t ws_size,
                              hipStream_t stream) {
    const float* z  = (const float*)d_in[0];
    const float* ls = (const float*)d_in[1];
    const float* lb = (const float*)d_in[2];
    const float* Wq = (const float*)d_in[3];
    const float* Wk = (const float*)d_in[4];
    const float* Wv = (const float*)d_in[5];
    const float* Wg = (const float*)d_in[6];
    const float* bg = (const float*)d_in[7];
    const float* Wo = (const float*)d_in[8];
    const float* bo = (const float*)d_in[9];
    float* out = (float*)d_out;
    short* wsp = (short*)d_ws;

    hipLaunchKernelGGL(ka_fused, dim3(2048), dim3(256), 0, stream,
                       z, ls, lb, Wq, Wk, Wv, Wg, bg, wsp);
    hipLaunchKernelGGL(k3_out, dim3(1024), dim3(256), 0, stream, wsp, Wo, bo, out);
}

// Round 7
// 160.728 us; speedup vs baseline: 1.0082x; 1.0082x over previous
//
#include <hip/hip_runtime.h>
#include <hip/hip_bf16.h>
#include <math.h>

// TriangleAttention — round 13: round-12 ring structure + softmax-denominator
// computed on the matrix pipe (l = ones^T @ P^T, one extra MFMA per PV step,
// replacing 256 VALU adds + 8 epilogue shuffles per wave) + unmasked kf loads
// (A-side garbage at k>=16 is annihilated by qa's structural zeros — round-10's
// NaN was solely the exp hazard, not this).
// HAZARD RULES (validated r10-r12): inline asm must NEVER read an MFMA dest
// directly (no compiler wait-states for INLINEASM) — a compiler-generated VALU
// op in between absorbs the hazard. Here: s[i]*L2E before exp2a;
// (lacc[0]+lacc[1])*0.5f before rcpa in the epilogue.
// BAN LIST (r7-8): __builtin_amdgcn_exp2f / __builtin_amdgcn_rcpf -> phantom
// scratch traffic. CANARY: WRITE_SIZE ~16.4 MB, FETCH ~66 MB, VGPR <= 128.
// B=2, L=256, D=64, H=4, Dh=16.
// ka: grid 2048=(bl,h), 4 waves; wave w owns queries [w*64, w*64+64).
//     S^T = K@Q^T -> P-lanes hold 4 consecutive j -> packed b64 P stores;
//     PV as O^T = V^T @ P^T; l via ones@P^T on the same pf frags.
//     znl staged through a 2-slot ring; Q^T single slot; P^T overlays ring.
//     37.1 KB LDS -> 4 blocks/CU.
// k3: out = sum_h GO_h @ Wo_h^T + bo (grid 1024); operand-swapped MFMA ->
//     transposed C fragment -> f32x4 vectorized stores.
//
// mfma_f32_16x16x32_bf16 layouts (verified rounds 2-5):
//   A[m = lane&15][k = quad*8 + u]
//   B[k = quad*8 + u][n = lane&15]
//   C/D: col = lane&15, row = quad*4 + reg

typedef __attribute__((ext_vector_type(4))) float f32x4;
typedef __attribute__((ext_vector_type(8))) short s16x8;

#define MFMA16(a, b, c) __builtin_amdgcn_mfma_f32_16x16x32_bf16((a), (b), (c), 0, 0, 0)

__device__ __forceinline__ float exp2a(float x) {   // raw v_exp_f32 (input MUST
    float r;                                        // be VALU-produced, not MFMA)
    asm("v_exp_f32 %0, %1" : "=v"(r) : "v"(x));
    return r;
}
__device__ __forceinline__ float rcpa(float x) {    // raw v_rcp_f32 (same rule)
    float r;
    asm("v_rcp_f32 %0, %1" : "=v"(r) : "v"(x));
    return r;
}

__device__ __forceinline__ unsigned pk2(float a, float b) {   // 2xf32 -> packed bf16x2 (RNE)
    union { __hip_bfloat162 h; unsigned u; } c;
    float2 t; t.x = a; t.y = b;
    c.h = __float22bfloat162_rn(t);
    return c.u;
}
__device__ __forceinline__ s16x8 cvt8(const float* p) {  // 8 fp32 -> bf16x8
    union { unsigned u[4]; s16x8 v; } r;
    r.u[0] = pk2(p[0], p[1]); r.u[1] = pk2(p[2], p[3]);
    r.u[2] = pk2(p[4], p[5]); r.u[3] = pk2(p[6], p[7]);
    return r.v;
}

// LDS map (shorts). Per-wave slice (2560 sh) at wsl = w*2560:
//   phase 1: ring slot s at [s*1024, +1024) (s=0,1); QT slot at [2048, +256)
//   phase 2: P^T(qt) at [qt*640, +640) (stride 40/row) — overlays ring+QT.
// Shared: KSH [256 pos][16 dh], VT [16 dh][264 pos-padded].
static constexpr int WSLICE = 2560;
static constexpr int ZNL = 0;          // 4 * 2560 = 10240 sh
static constexpr int KSH = 10240;      // 4096 sh
static constexpr int VT  = 14336;      // 4224 sh
static constexpr int LDS_EL = 18560;   // 37120 B -> 4 blocks/CU

__global__ __launch_bounds__(256, 3)
void ka_fused(const float* __restrict__ z, const float* __restrict__ ln_s,
              const float* __restrict__ ln_b, const float* __restrict__ Wq,
              const float* __restrict__ Wk, const float* __restrict__ Wv,
              const float* __restrict__ Wg, const float* __restrict__ bg,
              short* __restrict__ ws)
{
    __shared__ __align__(16) short lds[LDS_EL];
    const int tid = threadIdx.x, lane = tid & 63, w = tid >> 6;
    const int n16 = lane & 15, quad = lane >> 4;
    const bool qlo = (quad < 2);
    const int g = blockIdx.x, bl = g >> 2, h = g & 3;
    const size_t rowbase = (size_t)bl * (256 * 64);
    const int wsl = w * WSLICE;                    // wave's scratch slice

    // ---- LN: thread = position tid; pack row to bf16 in registers ----
    union { unsigned u[32]; s16x8 v8[8]; } row;
    {
        float zn[64];
        const float4* zp4 = (const float4*)(z + rowbase + (size_t)tid * 64);
        #pragma unroll
        for (int gq = 0; gq < 16; ++gq) {
            float4 v4 = zp4[gq];
            zn[gq * 4 + 0] = v4.x; zn[gq * 4 + 1] = v4.y;
            zn[gq * 4 + 2] = v4.z; zn[gq * 4 + 3] = v4.w;
        }
        float mu = 0.f;
        #pragma unroll
        for (int k = 0; k < 64; ++k) mu += zn[k];
        mu *= (1.f / 64.f);
        float va = 0.f;
        #pragma unroll
        for (int k = 0; k < 64; ++k) { float d = zn[k] - mu; va += d * d; }
        const float rs = rsqrtf(va * (1.f / 64.f) + 1e-5f);
        #pragma unroll
        for (int k = 0; k < 64; ++k) zn[k] = (zn[k] - mu) * rs * ln_s[k] + ln_b[k];
        #pragma unroll
        for (int k = 0; k < 32; ++k) row.u[k] = pk2(zn[2 * k], zn[2 * k + 1]);
    }

    auto store_row = [&](int slot) {               // swizzled row store into ring
        #pragma unroll
        for (int gq = 0; gq < 8; ++gq)
            *(s16x8*)&lds[ZNL + wsl + slot * 1024 + (lane & 15) * 64
                          + ((gq ^ (lane & 7)) * 8)] = row.v8[gq];
    };

    // ---- W head-slice frags (serve as A for Q/K/G-transposed, B for V) ----
    s16x8 bq[2], bk[2], bv[2], bgf[2];
    #pragma unroll
    for (int ks = 0; ks < 2; ++ks) {
        size_t off = (size_t)(h * 16 + n16) * 64 + ks * 32 + quad * 8;
        bq[ks] = cvt8(Wq + off);  bk[ks] = cvt8(Wk + off);
        bv[ks] = cvt8(Wv + off);  bgf[ks] = cvt8(Wg + off);
    }
    const float4 bg4 = *(const float4*)(bg + h * 16 + quad * 4);
    constexpr float QS  = 0.25f;                            // 1/sqrt(Dh); log2e at exp
    constexpr float L2E = 1.44269504088896340736f;

    float g4t[4][4];
    s16x8 qa[4];
    auto proj_tile = [&](int t, int s) {           // projections for tile t from ring slot s
        s16x8 zn0 = *(const s16x8*)&lds[ZNL + wsl + s * 1024 + n16 * 64
                                        + ((quad ^ (n16 & 7)) * 8)];
        s16x8 zn1 = *(const s16x8*)&lds[ZNL + wsl + s * 1024 + n16 * 64
                                        + (((4 + quad) ^ (n16 & 7)) * 8)];
        f32x4 aq = {}, ak = {}, av = {}, ag = {};
        aq = MFMA16(bq[0], zn0, aq);  aq = MFMA16(bq[1], zn1, aq);   // Q^T
        ak = MFMA16(bk[0], zn0, ak);  ak = MFMA16(bk[1], zn1, ak);   // K^T
        ag = MFMA16(bgf[0], zn0, ag); ag = MFMA16(bgf[1], zn1, ag);  // G^T
        av = MFMA16(zn0, bv[0], av);  av = MFMA16(zn1, bv[1], av);   // V
        {   // Q^T (scaled) -> single QT slot
            uint2 p = {pk2(aq[0] * QS, aq[1] * QS), pk2(aq[2] * QS, aq[3] * QS)};
            *(uint2*)&lds[ZNL + wsl + 2048 + n16 * 16 + quad * 4] = p;
        }
        {   // K^T -> KSH[pos][dh] (shared)
            uint2 p = {pk2(ak[0], ak[1]), pk2(ak[2], ak[3])};
            *(uint2*)&lds[KSH + (w * 64 + t * 16 + n16) * 16 + quad * 4] = p;
        }
        {   // V -> VT[dh][pos] (shared)
            uint2 p = {pk2(av[0], av[1]), pk2(av[2], av[3])};
            *(uint2*)&lds[VT + n16 * 264 + (w * 64 + t * 16 + quad * 4)] = p;
        }
        #pragma unroll
        for (int r = 0; r < 4; ++r)                 // gate (pos=n16, dh=q*4+r)
            g4t[t][r] = rcpa(1.f + __expf(-(ag[r] + bg4[r])));   // add absorbs hazard
        // Q^T B-frag for this tile, read back immediately (slot reused next tile;
        // DS ops are in-order within the wave). Quads 2,3 zero: Dh=16 < K=32.
        s16x8 q = {};
        if (qlo) q = *(const s16x8*)&lds[ZNL + wsl + 2048 + n16 * 16 + quad * 8];
        qa[t] = q;
    };

    // 2-deep staging ring: tiles 0,1 stored now; 2,3 held in regs until free.
    if (lane < 32) store_row(lane >> 4);           // tiles 0,1 -> slots 0,1
    proj_tile(0, 0);
    if (lane >= 32 && lane < 48) store_row(0);     // tile 2 -> slot 0
    proj_tile(1, 1);
    if (lane >= 48) store_row(1);                  // tile 3 -> slot 1
    proj_tile(2, 0);
    proj_tile(3, 1);
    __syncthreads();   // the ONLY barrier: KSH/VT visible

    // ---- attention: S^T = K@Q^T, P^T packed to LDS, O^T = V^T@P^T,
    //      l = ones @ P^T (matrix pipe, same pf frags) ----
    f32x4 o4[4], lacc[4];
    #pragma unroll
    for (int qt = 0; qt < 4; ++qt) { o4[qt] = {}; lacc[qt] = {}; }
    s16x8 ones;                                     // bf16 1.0 x8
    {
        union { unsigned u[4]; s16x8 v; } c;
        c.u[0] = 0x3F803F80u; c.u[1] = 0x3F803F80u;
        c.u[2] = 0x3F803F80u; c.u[3] = 0x3F803F80u;
        ones = c.v;
    }
    const int sw = (n16 ^ (n16 >> 2)) & 3;          // octet swizzle for P^T
    for (int ch = 0; ch < 8; ++ch) {                // 32 keys per chunk
        #pragma unroll
        for (int jtl = 0; jtl < 2; ++jtl) {
            int jt = ch * 2 + jtl;
            // Unmasked: quads 2,3 hold A-rows k=16..31 whose B-side (qa) is
            // structurally zero -> garbage annihilated. Address stays in-bounds.
            s16x8 kf = *(const s16x8*)&lds[KSH + (jt * 16 + n16) * 16 + quad * 8];
            const int po = (((jtl * 2 + (quad >> 1)) ^ sw) * 8) + (quad & 1) * 4;
            #pragma unroll
            for (int qt = 0; qt < 4; ++qt) {
                f32x4 zc = {};
                f32x4 s = MFMA16(kf, qa[qt], zc);   // S^T tile: col=i, row=j
                // v_mul (compiler VALU) absorbs the MFMA->read hazard, then the
                // asm v_exp reads a VALU result (hardware-interlocked).
                float e0 = exp2a(s[0] * L2E), e1 = exp2a(s[1] * L2E);
                float e2 = exp2a(s[2] * L2E), e3 = exp2a(s[3] * L2E);
                uint2 p = {pk2(e0, e1), pk2(e2, e3)};
                *(uint2*)&lds[ZNL + wsl + qt * 640 + n16 * 40 + po] = p;
            }
        }
        s16x8 vf = *(const s16x8*)&lds[VT + n16 * 264 + ch * 32 + quad * 8];
        #pragma unroll
        for (int qt = 0; qt < 4; ++qt) {
            s16x8 pf = *(const s16x8*)&lds[ZNL + wsl + qt * 640 + n16 * 40
                                           + ((quad ^ sw) * 8)];
            o4[qt]   = MFMA16(vf, pf, o4[qt]);      // O^T: col=i, row=dh
            lacc[qt] = MFMA16(ones, pf, lacc[qt]);  // l[i] replicated all rows
        }
    }

    // ---- epilogue: gate, direct coalesced GO stores (l replicated: no shfl) ----
    #pragma unroll
    for (int qt = 0; qt < 4; ++qt) {
        // Two compiler VALU ops (add, mul) absorb the MFMA->asm hazard on lacc.
        const float l = (lacc[qt][0] + lacc[qt][1]) * 0.5f;
        const float inv = rcpa(l);
        float g0 = g4t[qt][0] * o4[qt][0] * inv;
        float g1 = g4t[qt][1] * o4[qt][1] * inv;
        float g2 = g4t[qt][2] * o4[qt][2] * inv;
        float g3 = g4t[qt][3] * o4[qt][3] * inv;
        uint2 p = {pk2(g0, g1), pk2(g2, g3)};
        short* dst = ws + (((size_t)h * 512 + bl) * 256 + w * 64 + qt * 16 + n16) * 16
                     + quad * 4;
        *(uint2*)dst = p;
    }
}

// ---------------------------------------------------------------- kernel 3
// out = sum_h GO_h @ Wo_h^T + bo ; grid 1024 (bl,half), block 256, 32 rows/wave.
// Operand-swapped MFMA -> D col(lane&15) = row, D row(quad*4+r) = 4 consecutive
// out cols -> f32x4 stores.
__global__ __launch_bounds__(256, 4)
void k3_out(const short* __restrict__ ws, const float* __restrict__ Wo,
            const float* __restrict__ bo, float* __restrict__ out)
{
    const int tid = threadIdx.x, lane = tid & 63, w = tid >> 6;
    const int n16 = lane & 15, quad = lane >> 4;
    const short* GO = ws;
    const int bl = blockIdx.x >> 1, half = blockIdx.x & 1;
    const int rowloc = half * 128 + w * 32;

    s16x8 bfr[4][2];   // Wo[outd = nt*16+n16][ind = c*32 + quad*8 + u]
    #pragma unroll
    for (int nt = 0; nt < 4; ++nt)
        #pragma unroll
        for (int ks = 0; ks < 2; ++ks)
            bfr[nt][ks] = cvt8(Wo + (size_t)(nt * 16 + n16) * 64 + ks * 32 + quad * 8);

    f32x4 acc[2][4] = {};
    #pragma unroll
    for (int mt = 0; mt < 2; ++mt) {
        #pragma unroll
        for (int c = 0; c < 2; ++c) {
            int hp = c * 2 + (quad >> 1);
            const short* ap = &GO[(((size_t)hp * 512 + bl) * 256 + rowloc + mt * 16 + n16) * 16
                                  + (quad & 1) * 8];
            s16x8 a = *(const s16x8*)ap;
            #pragma unroll
            for (int nt = 0; nt < 4; ++nt)
                acc[mt][nt] = MFMA16(bfr[nt][c], a, acc[mt][nt]);   // swapped
        }
    }
    #pragma unroll
    for (int nt = 0; nt < 4; ++nt) {
        const float4 b4 = *(const float4*)(bo + nt * 16 + quad * 4);
        f32x4 b4v; b4v[0] = b4.x; b4v[1] = b4.y; b4v[2] = b4.z; b4v[3] = b4.w;
        #pragma unroll
        for (int mt = 0; mt < 2; ++mt) {
            f32x4 v = acc[mt][nt] + b4v;
            *(f32x4*)&out[((size_t)bl * 256 + rowloc + mt * 16 + n16) * 64
                          + nt * 16 + quad * 4] = v;
        }
    }
}

extern "C" void kernel_launch(void* const* d_in, const int* in_sizes, int n_in,
                              void* d_out, int out_size, void* d_ws, size_t ws_size,
                              hipStream_t stream) {
    const float* z  = (const float*)d_in[0];
    const float* ls = (const float*)d_in[1];
    const float* lb = (const float*)d_in[2];
    const float* Wq = (const float*)d_in[3];
    const float* Wk = (const float*)d_in[4];
    const float* Wv = (const float*)d_in[5];
    const float* Wg = (const float*)d_in[6];
    const float* bg = (const float*)d_in[7];
    const float* Wo = (const float*)d_in[8];
    const float* bo = (const float*)d_in[9];
    float* out = (float*)d_out;
    short* wsp = (short*)d_ws;

    hipLaunchKernelGGL(ka_fused, dim3(2048), dim3(256), 0, stream,
                       z, ls, lb, Wq, Wk, Wv, Wg, bg, wsp);
    hipLaunchKernelGGL(k3_out, dim3(1024), dim3(256), 0, stream, wsp, Wo, bo, out);
}

// Round 8
// 155.050 us; speedup vs baseline: 1.0451x; 1.0366x over previous
//
#include <hip/hip_runtime.h>
#include <hip/hip_bf16.h>
#include <math.h>

// TriangleAttention — round 14: attention loop moved to 16x16x16 MFMA.
// Key identity: with S^T = K@Q^T at K=16, the S^T output fragment
// (reg r = P[key=quad*4+r][i=n16]) IS the PV B-fragment (B[k=quad*4+u][n=i]) —
// so P stays in registers (no LDS round-trip), and the Q^T projection output
// fragment IS the QK B-fragment — so Q stays in registers too. DS traffic in
// the attention loop drops 15 -> 4 instrs/chunk (kf/vf b64 reads only).
// QK at K=16 also stops wasting half of every MFMA (Dh=16, old K=32 was
// half zeros + exec-mask juggling).
// HAZARD RULES (r10-r12): inline asm never reads an MFMA dest directly —
// compiler VALU in between (s[i]*L2E, gate add, lacc add) absorbs wait-states.
// Asm-MFMA fallback (if builtin absent) self-fences with s_nops.
// BAN LIST (r7-8): __builtin_amdgcn_exp2f / __builtin_amdgcn_rcpf.
// CANARY: WRITE_SIZE ~16.4 MB, FETCH ~66 MB, VGPR <= 128.
// B=2, L=256, D=64, H=4, Dh=16.
// ka: grid 2048=(bl,h), 4 waves; wave w owns queries [w*64, +64).
//     znl 2-slot ring (r12); KSH [256 pos][20 pad] b64-frags; VT [16 dh][264].
//     35.1 KB LDS -> 4 blocks/CU. l = ones@P on the matrix pipe (r13).
// k3: out = sum_h GO_h @ Wo_h^T + bo (grid 1024); operand-swapped MFMA ->
//     f32x4 stores. Unchanged.
//
// 16x16x32 layouts (verified r2-5):  A[m=lane&15][k=quad*8+u],
//   B[k=quad*8+u][n=lane&15], C/D: col=lane&15, row=quad*4+reg.
// 16x16x16 layouts (standard CDNA, same family): A[m=lane&15][k=quad*4+u],
//   B[k=quad*4+u][n=lane&15], C/D identical to above.

typedef __attribute__((ext_vector_type(4))) float f32x4;
typedef __attribute__((ext_vector_type(8))) short s16x8;
typedef __attribute__((ext_vector_type(4))) short s16x4;

#define MFMA16(a, b, c) __builtin_amdgcn_mfma_f32_16x16x32_bf16((a), (b), (c), 0, 0, 0)

__device__ __forceinline__ f32x4 mfma16b(s16x4 a, s16x4 b, f32x4 c) {
#if __has_builtin(__builtin_amdgcn_mfma_f32_16x16x16bf16_1k)
    return __builtin_amdgcn_mfma_f32_16x16x16bf16_1k(a, b, c, 0, 0, 0);
#elif __has_builtin(__builtin_amdgcn_mfma_f32_16x16x16_bf16)
    return __builtin_amdgcn_mfma_f32_16x16x16_bf16(a, b, c, 0, 0, 0);
#else
    // Fallback: explicit instruction with conservative self-fencing (the
    // compiler inserts no wait-states around INLINEASM — r10 lesson).
    f32x4 d;
    asm volatile("s_nop 1\n\t"
                 "v_mfma_f32_16x16x16_bf16 %0, %1, %2, %3\n\t"
                 "s_nop 7\n\t"
                 "s_nop 7"
                 : "=v"(d) : "v"(a), "v"(b), "v"(c));
    return d;
#endif
}

__device__ __forceinline__ float exp2a(float x) {   // raw v_exp_f32 (input MUST
    float r;                                        // be VALU-produced, not MFMA)
    asm("v_exp_f32 %0, %1" : "=v"(r) : "v"(x));
    return r;
}
__device__ __forceinline__ float rcpa(float x) {    // raw v_rcp_f32 (same rule)
    float r;
    asm("v_rcp_f32 %0, %1" : "=v"(r) : "v"(x));
    return r;
}

__device__ __forceinline__ unsigned pk2(float a, float b) {   // 2xf32 -> packed bf16x2 (RNE)
    union { __hip_bfloat162 h; unsigned u; } c;
    float2 t; t.x = a; t.y = b;
    c.h = __float22bfloat162_rn(t);
    return c.u;
}
__device__ __forceinline__ s16x8 cvt8(const float* p) {  // 8 fp32 -> bf16x8
    union { unsigned u[4]; s16x8 v; } r;
    r.u[0] = pk2(p[0], p[1]); r.u[1] = pk2(p[2], p[3]);
    r.u[2] = pk2(p[4], p[5]); r.u[3] = pk2(p[6], p[7]);
    return r.v;
}

// LDS map (shorts). Per-wave slice (2048 sh) at wsl = w*2048:
//   ring slot s at [s*1024, +1024) (s=0,1). (No QT slot, no P^T — in-register.)
// Shared: KSH [256 pos][20 sh pad] (dh 0..15 used), VT [16 dh][264 pos-pad].
static constexpr int WSLICE = 2048;
static constexpr int ZNL = 0;          // 4 * 2048 = 8192 sh
static constexpr int KSH = 8192;       // 256*20 = 5120 sh
static constexpr int VT  = 13312;      // 4224 sh
static constexpr int LDS_EL = 17536;   // 35072 B -> 4 blocks/CU

__global__ __launch_bounds__(256, 3)
void ka_fused(const float* __restrict__ z, const float* __restrict__ ln_s,
              const float* __restrict__ ln_b, const float* __restrict__ Wq,
              const float* __restrict__ Wk, const float* __restrict__ Wv,
              const float* __restrict__ Wg, const float* __restrict__ bg,
              short* __restrict__ ws)
{
    __shared__ __align__(16) short lds[LDS_EL];
    const int tid = threadIdx.x, lane = tid & 63, w = tid >> 6;
    const int n16 = lane & 15, quad = lane >> 4;
    const int g = blockIdx.x, bl = g >> 2, h = g & 3;
    const size_t rowbase = (size_t)bl * (256 * 64);
    const int wsl = w * WSLICE;                    // wave's scratch slice

    // ---- LN: thread = position tid; pack row to bf16 in registers ----
    union { unsigned u[32]; s16x8 v8[8]; } row;
    {
        float zn[64];
        const float4* zp4 = (const float4*)(z + rowbase + (size_t)tid * 64);
        #pragma unroll
        for (int gq = 0; gq < 16; ++gq) {
            float4 v4 = zp4[gq];
            zn[gq * 4 + 0] = v4.x; zn[gq * 4 + 1] = v4.y;
            zn[gq * 4 + 2] = v4.z; zn[gq * 4 + 3] = v4.w;
        }
        float mu = 0.f;
        #pragma unroll
        for (int k = 0; k < 64; ++k) mu += zn[k];
        mu *= (1.f / 64.f);
        float va = 0.f;
        #pragma unroll
        for (int k = 0; k < 64; ++k) { float d = zn[k] - mu; va += d * d; }
        const float rs = rsqrtf(va * (1.f / 64.f) + 1e-5f);
        #pragma unroll
        for (int k = 0; k < 64; ++k) zn[k] = (zn[k] - mu) * rs * ln_s[k] + ln_b[k];
        #pragma unroll
        for (int k = 0; k < 32; ++k) row.u[k] = pk2(zn[2 * k], zn[2 * k + 1]);
    }

    auto store_row = [&](int slot) {               // swizzled row store into ring
        #pragma unroll
        for (int gq = 0; gq < 8; ++gq)
            *(s16x8*)&lds[ZNL + wsl + slot * 1024 + (lane & 15) * 64
                          + ((gq ^ (lane & 7)) * 8)] = row.v8[gq];
    };

    // ---- W head-slice frags (serve as A for Q/K/G-transposed, B for V) ----
    s16x8 bq[2], bk[2], bv[2], bgf[2];
    #pragma unroll
    for (int ks = 0; ks < 2; ++ks) {
        size_t off = (size_t)(h * 16 + n16) * 64 + ks * 32 + quad * 8;
        bq[ks] = cvt8(Wq + off);  bk[ks] = cvt8(Wk + off);
        bv[ks] = cvt8(Wv + off);  bgf[ks] = cvt8(Wg + off);
    }
    const float4 bg4 = *(const float4*)(bg + h * 16 + quad * 4);
    constexpr float QS  = 0.25f;                            // 1/sqrt(Dh); log2e at exp
    constexpr float L2E = 1.44269504088896340736f;

    float g4t[4][4];
    s16x4 qa4[4];                                  // Q^T B-frags, in-register
    auto proj_tile = [&](int t, int s) {           // projections for tile t from ring slot s
        s16x8 zn0 = *(const s16x8*)&lds[ZNL + wsl + s * 1024 + n16 * 64
                                        + ((quad ^ (n16 & 7)) * 8)];
        s16x8 zn1 = *(const s16x8*)&lds[ZNL + wsl + s * 1024 + n16 * 64
                                        + (((4 + quad) ^ (n16 & 7)) * 8)];
        f32x4 aq = {}, ak = {}, av = {}, ag = {};
        aq = MFMA16(bq[0], zn0, aq);  aq = MFMA16(bq[1], zn1, aq);   // Q^T
        ak = MFMA16(bk[0], zn0, ak);  ak = MFMA16(bk[1], zn1, ak);   // K^T
        ag = MFMA16(bgf[0], zn0, ag); ag = MFMA16(bgf[1], zn1, ag);  // G^T
        av = MFMA16(zn0, bv[0], av);  av = MFMA16(zn1, bv[1], av);   // V
        {   // Q^T (scaled) -> in-register B-frag: lane holds Q^T[dh=quad*4+r][i=n16]
            union { unsigned u[2]; s16x4 v; } q;
            q.u[0] = pk2(aq[0] * QS, aq[1] * QS);
            q.u[1] = pk2(aq[2] * QS, aq[3] * QS);
            qa4[t] = q.v;
        }
        {   // K^T -> KSH[pos][dh] (stride 20, conflict-free b64 frags)
            uint2 p = {pk2(ak[0], ak[1]), pk2(ak[2], ak[3])};
            *(uint2*)&lds[KSH + (w * 64 + t * 16 + n16) * 20 + quad * 4] = p;
        }
        {   // V -> VT[dh][pos] (shared)
            uint2 p = {pk2(av[0], av[1]), pk2(av[2], av[3])};
            *(uint2*)&lds[VT + n16 * 264 + (w * 64 + t * 16 + quad * 4)] = p;
        }
        #pragma unroll
        for (int r = 0; r < 4; ++r)                 // gate (pos=n16, dh=q*4+r)
            g4t[t][r] = rcpa(1.f + __expf(-(ag[r] + bg4[r])));   // add absorbs hazard
    };

    // 2-deep staging ring: tiles 0,1 stored now; 2,3 held in regs until free.
    if (lane < 32) store_row(lane >> 4);           // tiles 0,1 -> slots 0,1
    proj_tile(0, 0);
    if (lane >= 32 && lane < 48) store_row(0);     // tile 2 -> slot 0
    proj_tile(1, 1);
    if (lane >= 48) store_row(1);                  // tile 3 -> slot 1
    proj_tile(2, 0);
    proj_tile(3, 1);
    __syncthreads();   // the ONLY barrier: KSH/VT visible

    // ---- attention, all 16x16x16: S^T = K@Q^T; P in-register; O^T = V^T@P^T;
    //      l = ones@P^T on the matrix pipe ----
    f32x4 o4[4], lacc[4];
    #pragma unroll
    for (int qt = 0; qt < 4; ++qt) { o4[qt] = {}; lacc[qt] = {}; }
    s16x4 ones4;                                    // bf16 1.0 x4
    {
        union { unsigned u[2]; s16x4 v; } c;
        c.u[0] = 0x3F803F80u; c.u[1] = 0x3F803F80u;
        ones4 = c.v;
    }
    const int kbase = KSH + n16 * 20 + quad * 4;    // + jt*320
    const int vbase = VT + n16 * 264 + quad * 4;    // + jt*16
    for (int ch = 0; ch < 8; ++ch) {                // 32 keys per chunk
        #pragma unroll
        for (int jtl = 0; jtl < 2; ++jtl) {
            const int jt = ch * 2 + jtl;
            // kf: A[m=key=n16][k=dh=quad*4+u]; vf: A[m=dh=n16][k=key=quad*4+u]
            s16x4 kf = *(const s16x4*)&lds[kbase + jt * 320];
            s16x4 vf = *(const s16x4*)&lds[vbase + jt * 16];
            #pragma unroll
            for (int qt = 0; qt < 4; ++qt) {
                f32x4 zc = {};
                f32x4 s = mfma16b(kf, qa4[qt], zc);  // S^T: reg r = P-row key=quad*4+r, col i=n16
                // v_mul (compiler VALU) absorbs the MFMA->read hazard, then the
                // asm v_exp reads a VALU result (hardware-interlocked).
                float e0 = exp2a(s[0] * L2E), e1 = exp2a(s[1] * L2E);
                float e2 = exp2a(s[2] * L2E), e3 = exp2a(s[3] * L2E);
                union { unsigned u[2]; s16x4 v; } pb;
                pb.u[0] = pk2(e0, e1); pb.u[1] = pk2(e2, e3);
                // pb IS the PV B-frag: B[k=key=quad*4+u][n=i=n16]
                o4[qt]   = mfma16b(vf, pb.v, o4[qt]);     // O^T: col=i, row=dh
                lacc[qt] = mfma16b(ones4, pb.v, lacc[qt]); // l[i], all rows
            }
        }
    }

    // ---- epilogue: gate, direct coalesced GO stores (l replicated: no shfl) ----
    #pragma unroll
    for (int qt = 0; qt < 4; ++qt) {
        // Two compiler VALU ops (add, mul) absorb the MFMA->asm hazard on lacc.
        const float l = (lacc[qt][0] + lacc[qt][1]) * 0.5f;
        const float inv = rcpa(l);
        float g0 = g4t[qt][0] * o4[qt][0] * inv;
        float g1 = g4t[qt][1] * o4[qt][1] * inv;
        float g2 = g4t[qt][2] * o4[qt][2] * inv;
        float g3 = g4t[qt][3] * o4[qt][3] * inv;
        uint2 p = {pk2(g0, g1), pk2(g2, g3)};
        short* dst = ws + (((size_t)h * 512 + bl) * 256 + w * 64 + qt * 16 + n16) * 16
                     + quad * 4;
        *(uint2*)dst = p;
    }
}

// ---------------------------------------------------------------- kernel 3
// out = sum_h GO_h @ Wo_h^T + bo ; grid 1024 (bl,half), block 256, 32 rows/wave.
// Operand-swapped MFMA -> D col(lane&15) = row, D row(quad*4+r) = 4 consecutive
// out cols -> f32x4 stores.
__global__ __launch_bounds__(256, 4)
void k3_out(const short* __restrict__ ws, const float* __restrict__ Wo,
            const float* __restrict__ bo, float* __restrict__ out)
{
    const int tid = threadIdx.x, lane = tid & 63, w = tid >> 6;
    const int n16 = lane & 15, quad = lane >> 4;
    const short* GO = ws;
    const int bl = blockIdx.x >> 1, half = blockIdx.x & 1;
    const int rowloc = half * 128 + w * 32;

    s16x8 bfr[4][2];   // Wo[outd = nt*16+n16][ind = c*32 + quad*8 + u]
    #pragma unroll
    for (int nt = 0; nt < 4; ++nt)
        #pragma unroll
        for (int ks = 0; ks < 2; ++ks)
            bfr[nt][ks] = cvt8(Wo + (size_t)(nt * 16 + n16) * 64 + ks * 32 + quad * 8);

    f32x4 acc[2][4] = {};
    #pragma unroll
    for (int mt = 0; mt < 2; ++mt) {
        #pragma unroll
        for (int c = 0; c < 2; ++c) {
            int hp = c * 2 + (quad >> 1);
            const short* ap = &GO[(((size_t)hp * 512 + bl) * 256 + rowloc + mt * 16 + n16) * 16
                                  + (quad & 1) * 8];
            s16x8 a = *(const s16x8*)ap;
            #pragma unroll
            for (int nt = 0; nt < 4; ++nt)
                acc[mt][nt] = MFMA16(bfr[nt][c], a, acc[mt][nt]);   // swapped
        }
    }
    #pragma unroll
    for (int nt = 0; nt < 4; ++nt) {
        const float4 b4 = *(const float4*)(bo + nt * 16 + quad * 4);
        f32x4 b4v; b4v[0] = b4.x; b4v[1] = b4.y; b4v[2] = b4.z; b4v[3] = b4.w;
        #pragma unroll
        for (int mt = 0; mt < 2; ++mt) {
            f32x4 v = acc[mt][nt] + b4v;
            *(f32x4*)&out[((size_t)bl * 256 + rowloc + mt * 16 + n16) * 64
                          + nt * 16 + quad * 4] = v;
        }
    }
}

extern "C" void kernel_launch(void* const* d_in, const int* in_sizes, int n_in,
                              void* d_out, int out_size, void* d_ws, size_t ws_size,
                              hipStream_t stream) {
    const float* z  = (const float*)d_in[0];
    const float* ls = (const float*)d_in[1];
    const float* lb = (const float*)d_in[2];
    const float* Wq = (const float*)d_in[3];
    const float* Wk = (const float*)d_in[4];
    const float* Wv = (const float*)d_in[5];
    const float* Wg = (const float*)d_in[6];
    const float* bg = (const float*)d_in[7];
    const float* Wo = (const float*)d_in[8];
    const float* bo = (const float*)d_in[9];
    float* out = (float*)d_out;
    short* wsp = (short*)d_ws;

    hipLaunchKernelGGL(ka_fused, dim3(2048), dim3(256), 0, stream,
                       z, ls, lb, Wq, Wk, Wv, Wg, bg, wsp);
    hipLaunchKernelGGL(k3_out, dim3(1024), dim3(256), 0, stream, wsp, Wo, bo, out);
}

// Round 9
// 149.821 us; speedup vs baseline: 1.0816x; 1.0349x over previous
//
#include <hip/hip_runtime.h>
#include <hip/hip_bf16.h>
#include <math.h>

// TriangleAttention — round 15: single-slot znl staging (in-order DS pipe makes
// the 2-slot ring unnecessary: store(t) -> proj(t) -> store(t+1) is safe
// because same-wave LDS ops execute in issue order — validated r12/r14) ->
// LDS 35.3 KB -> 26.9 KB -> 6 blocks/CU (was 4). Gate sigmoid moved off libm
// __expf onto the validated mul+exp2a pattern.
// HAZARD RULES (r10-r14): inline asm never reads an MFMA dest directly —
// a compiler-generated VALU op in between (s*L2E mul / ag+bg add) absorbs the
// required wait-states. BAN LIST (r7-8): __builtin_amdgcn_exp2f/rcpf.
// CANARY: WRITE_SIZE ~16.4 MB, FETCH ~66 MB, VGPR <= ~100, absmax <= 0.0155.
// B=2, L=256, D=64, H=4, Dh=16.
// ka: grid 2048=(bl,h), 4 waves; wave w owns queries [w*64, +64).
//     16x16x16 attention (r14): S^T = K@Q^T with Q/P in registers (the S^T
//     output fragment IS the PV B-fragment; the Q^T projection output fragment
//     IS the QK B-fragment). DS in attention loop: 2 b64 reads per 16 keys.
//     l = ones@P on the matrix pipe (r13). KSH [256][20] pad, VT [16][264].
// k3: out = sum_h GO_h @ Wo_h^T + bo (grid 1024); operand-swapped MFMA ->
//     f32x4 stores. Unchanged.
//
// 16x16x32 layouts (verified r2-5):  A[m=lane&15][k=quad*8+u],
//   B[k=quad*8+u][n=lane&15], C/D: col=lane&15, row=quad*4+reg.
// 16x16x16 layouts (verified r14): A[m=lane&15][k=quad*4+u],
//   B[k=quad*4+u][n=lane&15], C/D identical to above.

typedef __attribute__((ext_vector_type(4))) float f32x4;
typedef __attribute__((ext_vector_type(8))) short s16x8;
typedef __attribute__((ext_vector_type(4))) short s16x4;

#define MFMA16(a, b, c) __builtin_amdgcn_mfma_f32_16x16x32_bf16((a), (b), (c), 0, 0, 0)

__device__ __forceinline__ f32x4 mfma16b(s16x4 a, s16x4 b, f32x4 c) {
#if __has_builtin(__builtin_amdgcn_mfma_f32_16x16x16bf16_1k)
    return __builtin_amdgcn_mfma_f32_16x16x16bf16_1k(a, b, c, 0, 0, 0);
#elif __has_builtin(__builtin_amdgcn_mfma_f32_16x16x16_bf16)
    return __builtin_amdgcn_mfma_f32_16x16x16_bf16(a, b, c, 0, 0, 0);
#else
    f32x4 d;
    asm volatile("s_nop 1\n\t"
                 "v_mfma_f32_16x16x16_bf16 %0, %1, %2, %3\n\t"
                 "s_nop 7\n\t"
                 "s_nop 7"
                 : "=v"(d) : "v"(a), "v"(b), "v"(c));
    return d;
#endif
}

__device__ __forceinline__ float exp2a(float x) {   // raw v_exp_f32 (input MUST
    float r;                                        // be VALU-produced, not MFMA)
    asm("v_exp_f32 %0, %1" : "=v"(r) : "v"(x));
    return r;
}
__device__ __forceinline__ float rcpa(float x) {    // raw v_rcp_f32 (same rule)
    float r;
    asm("v_rcp_f32 %0, %1" : "=v"(r) : "v"(x));
    return r;
}

__device__ __forceinline__ unsigned pk2(float a, float b) {   // 2xf32 -> packed bf16x2 (RNE)
    union { __hip_bfloat162 h; unsigned u; } c;
    float2 t; t.x = a; t.y = b;
    c.h = __float22bfloat162_rn(t);
    return c.u;
}
__device__ __forceinline__ s16x8 cvt8(const float* p) {  // 8 fp32 -> bf16x8
    union { unsigned u[4]; s16x8 v; } r;
    r.u[0] = pk2(p[0], p[1]); r.u[1] = pk2(p[2], p[3]);
    r.u[2] = pk2(p[4], p[5]); r.u[3] = pk2(p[6], p[7]);
    return r.v;
}

// LDS map (shorts). Per-wave znl slot (1024 sh) at wsl = w*1024 — SINGLE slot:
// same-wave DS ordering guarantees proj(t)'s reads complete before store(t+1)'s
// writes land (in-order pipe), so no double-buffer and no barriers needed.
// Shared: KSH [256 pos][20 sh pad], VT [16 dh][264 pos-pad].
static constexpr int WSLICE = 1024;
static constexpr int ZNL = 0;          // 4 * 1024 = 4096 sh
static constexpr int KSH = 4096;       // 256*20 = 5120 sh
static constexpr int VT  = 9216;       // 16*264 = 4224 sh
static constexpr int LDS_EL = 13440;   // 26880 B -> 6 blocks/CU

__global__ __launch_bounds__(256, 3)
void ka_fused(const float* __restrict__ z, const float* __restrict__ ln_s,
              const float* __restrict__ ln_b, const float* __restrict__ Wq,
              const float* __restrict__ Wk, const float* __restrict__ Wv,
              const float* __restrict__ Wg, const float* __restrict__ bg,
              short* __restrict__ ws)
{
    __shared__ __align__(16) short lds[LDS_EL];
    const int tid = threadIdx.x, lane = tid & 63, w = tid >> 6;
    const int n16 = lane & 15, quad = lane >> 4;
    const int g = blockIdx.x, bl = g >> 2, h = g & 3;
    const size_t rowbase = (size_t)bl * (256 * 64);
    const int wsl = w * WSLICE;                    // wave's staging slot

    // ---- LN: thread = position tid; pack row to bf16 in registers ----
    union { unsigned u[32]; s16x8 v8[8]; } row;
    {
        float zn[64];
        const float4* zp4 = (const float4*)(z + rowbase + (size_t)tid * 64);
        #pragma unroll
        for (int gq = 0; gq < 16; ++gq) {
            float4 v4 = zp4[gq];
            zn[gq * 4 + 0] = v4.x; zn[gq * 4 + 1] = v4.y;
            zn[gq * 4 + 2] = v4.z; zn[gq * 4 + 3] = v4.w;
        }
        float mu = 0.f;
        #pragma unroll
        for (int k = 0; k < 64; ++k) mu += zn[k];
        mu *= (1.f / 64.f);
        float va = 0.f;
        #pragma unroll
        for (int k = 0; k < 64; ++k) { float d = zn[k] - mu; va += d * d; }
        const float rs = rsqrtf(va * (1.f / 64.f) + 1e-5f);
        #pragma unroll
        for (int k = 0; k < 64; ++k) zn[k] = (zn[k] - mu) * rs * ln_s[k] + ln_b[k];
        #pragma unroll
        for (int k = 0; k < 32; ++k) row.u[k] = pk2(zn[2 * k], zn[2 * k + 1]);
    }

    auto store_row = [&]() {                       // swizzled row store into slot
        #pragma unroll
        for (int gq = 0; gq < 8; ++gq)
            *(s16x8*)&lds[ZNL + wsl + (lane & 15) * 64
                          + ((gq ^ (lane & 7)) * 8)] = row.v8[gq];
    };

    // ---- W head-slice frags (serve as A for Q/K/G-transposed, B for V) ----
    s16x8 bq[2], bk[2], bv[2], bgf[2];
    #pragma unroll
    for (int ks = 0; ks < 2; ++ks) {
        size_t off = (size_t)(h * 16 + n16) * 64 + ks * 32 + quad * 8;
        bq[ks] = cvt8(Wq + off);  bk[ks] = cvt8(Wk + off);
        bv[ks] = cvt8(Wv + off);  bgf[ks] = cvt8(Wg + off);
    }
    const float4 bg4 = *(const float4*)(bg + h * 16 + quad * 4);
    constexpr float QS  = 0.25f;                            // 1/sqrt(Dh); log2e at exp
    constexpr float L2E = 1.44269504088896340736f;

    float g4t[4][4];
    s16x4 qa4[4];                                  // Q^T B-frags, in-register
    auto proj_tile = [&](int t) {                  // projections for tile t
        s16x8 zn0 = *(const s16x8*)&lds[ZNL + wsl + n16 * 64
                                        + ((quad ^ (n16 & 7)) * 8)];
        s16x8 zn1 = *(const s16x8*)&lds[ZNL + wsl + n16 * 64
                                        + (((4 + quad) ^ (n16 & 7)) * 8)];
        f32x4 aq = {}, ak = {}, av = {}, ag = {};
        aq = MFMA16(bq[0], zn0, aq);  aq = MFMA16(bq[1], zn1, aq);   // Q^T
        ak = MFMA16(bk[0], zn0, ak);  ak = MFMA16(bk[1], zn1, ak);   // K^T
        ag = MFMA16(bgf[0], zn0, ag); ag = MFMA16(bgf[1], zn1, ag);  // G^T
        av = MFMA16(zn0, bv[0], av);  av = MFMA16(zn1, bv[1], av);   // V
        {   // Q^T (scaled) -> in-register B-frag: lane holds Q^T[dh=quad*4+r][i=n16]
            union { unsigned u[2]; s16x4 v; } q;
            q.u[0] = pk2(aq[0] * QS, aq[1] * QS);
            q.u[1] = pk2(aq[2] * QS, aq[3] * QS);
            qa4[t] = q.v;
        }
        {   // K^T -> KSH[pos][dh] (stride 20, conflict-free b64 frags)
            uint2 p = {pk2(ak[0], ak[1]), pk2(ak[2], ak[3])};
            *(uint2*)&lds[KSH + (w * 64 + t * 16 + n16) * 20 + quad * 4] = p;
        }
        {   // V -> VT[dh][pos] (shared)
            uint2 p = {pk2(av[0], av[1]), pk2(av[2], av[3])};
            *(uint2*)&lds[VT + n16 * 264 + (w * 64 + t * 16 + quad * 4)] = p;
        }
        #pragma unroll
        for (int r = 0; r < 4; ++r) {               // gate (pos=n16, dh=q*4+r)
            float x = ag[r] + bg4[r];               // VALU add absorbs MFMA hazard
            g4t[t][r] = rcpa(1.f + exp2a(x * -L2E)); // sigmoid via raw exp2/rcp
        }
    };

    // Single-slot staging: in-order DS guarantees proj(t) reads precede
    // store(t+1) writes. Lane-group t owns tile t's rows.
    if ((lane >> 4) == 0) store_row();
    proj_tile(0);
    if ((lane >> 4) == 1) store_row();
    proj_tile(1);
    if ((lane >> 4) == 2) store_row();
    proj_tile(2);
    if ((lane >> 4) == 3) store_row();
    proj_tile(3);
    __syncthreads();   // the ONLY barrier: KSH/VT visible

    // ---- attention, all 16x16x16: S^T = K@Q^T; P in-register; O^T = V^T@P^T;
    //      l = ones@P^T on the matrix pipe ----
    f32x4 o4[4], lacc[4];
    #pragma unroll
    for (int qt = 0; qt < 4; ++qt) { o4[qt] = {}; lacc[qt] = {}; }
    s16x4 ones4;                                    // bf16 1.0 x4
    {
        union { unsigned u[2]; s16x4 v; } c;
        c.u[0] = 0x3F803F80u; c.u[1] = 0x3F803F80u;
        ones4 = c.v;
    }
    const int kbase = KSH + n16 * 20 + quad * 4;    // + jt*320
    const int vbase = VT + n16 * 264 + quad * 4;    // + jt*16
    for (int ch = 0; ch < 8; ++ch) {                // 32 keys per chunk
        #pragma unroll
        for (int jtl = 0; jtl < 2; ++jtl) {
            const int jt = ch * 2 + jtl;
            // kf: A[m=key=n16][k=dh=quad*4+u]; vf: A[m=dh=n16][k=key=quad*4+u]
            s16x4 kf = *(const s16x4*)&lds[kbase + jt * 320];
            s16x4 vf = *(const s16x4*)&lds[vbase + jt * 16];
            #pragma unroll
            for (int qt = 0; qt < 4; ++qt) {
                f32x4 zc = {};
                f32x4 s = mfma16b(kf, qa4[qt], zc);  // S^T: reg r = P-row key=quad*4+r, col i=n16
                // v_mul (compiler VALU) absorbs the MFMA->read hazard, then the
                // asm v_exp reads a VALU result (hardware-interlocked).
                float e0 = exp2a(s[0] * L2E), e1 = exp2a(s[1] * L2E);
                float e2 = exp2a(s[2] * L2E), e3 = exp2a(s[3] * L2E);
                union { unsigned u[2]; s16x4 v; } pb;
                pb.u[0] = pk2(e0, e1); pb.u[1] = pk2(e2, e3);
                // pb IS the PV B-frag: B[k=key=quad*4+u][n=i=n16]
                o4[qt]   = mfma16b(vf, pb.v, o4[qt]);      // O^T: col=i, row=dh
                lacc[qt] = mfma16b(ones4, pb.v, lacc[qt]); // l[i], all rows
            }
        }
    }

    // ---- epilogue: gate, direct coalesced GO stores (l replicated: no shfl) ----
    #pragma unroll
    for (int qt = 0; qt < 4; ++qt) {
        // Two compiler VALU ops (add, mul) absorb the MFMA->asm hazard on lacc.
        const float l = (lacc[qt][0] + lacc[qt][1]) * 0.5f;
        const float inv = rcpa(l);
        float g0 = g4t[qt][0] * o4[qt][0] * inv;
        float g1 = g4t[qt][1] * o4[qt][1] * inv;
        float g2 = g4t[qt][2] * o4[qt][2] * inv;
        float g3 = g4t[qt][3] * o4[qt][3] * inv;
        uint2 p = {pk2(g0, g1), pk2(g2, g3)};
        short* dst = ws + (((size_t)h * 512 + bl) * 256 + w * 64 + qt * 16 + n16) * 16
                     + quad * 4;
        *(uint2*)dst = p;
    }
}

// ---------------------------------------------------------------- kernel 3
// out = sum_h GO_h @ Wo_h^T + bo ; grid 1024 (bl,half), block 256, 32 rows/wave.
// Operand-swapped MFMA -> D col(lane&15) = row, D row(quad*4+r) = 4 consecutive
// out cols -> f32x4 stores.
__global__ __launch_bounds__(256, 4)
void k3_out(const short* __restrict__ ws, const float* __restrict__ Wo,
            const float* __restrict__ bo, float* __restrict__ out)
{
    const int tid = threadIdx.x, lane = tid & 63, w = tid >> 6;
    const int n16 = lane & 15, quad = lane >> 4;
    const short* GO = ws;
    const int bl = blockIdx.x >> 1, half = blockIdx.x & 1;
    const int rowloc = half * 128 + w * 32;

    s16x8 bfr[4][2];   // Wo[outd = nt*16+n16][ind = c*32 + quad*8 + u]
    #pragma unroll
    for (int nt = 0; nt < 4; ++nt)
        #pragma unroll
        for (int ks = 0; ks < 2; ++ks)
            bfr[nt][ks] = cvt8(Wo + (size_t)(nt * 16 + n16) * 64 + ks * 32 + quad * 8);

    f32x4 acc[2][4] = {};
    #pragma unroll
    for (int mt = 0; mt < 2; ++mt) {
        #pragma unroll
        for (int c = 0; c < 2; ++c) {
            int hp = c * 2 + (quad >> 1);
            const short* ap = &GO[(((size_t)hp * 512 + bl) * 256 + rowloc + mt * 16 + n16) * 16
                                  + (quad & 1) * 8];
            s16x8 a = *(const s16x8*)ap;
            #pragma unroll
            for (int nt = 0; nt < 4; ++nt)
                acc[mt][nt] = MFMA16(bfr[nt][c], a, acc[mt][nt]);   // swapped
        }
    }
    #pragma unroll
    for (int nt = 0; nt < 4; ++nt) {
        const float4 b4 = *(const float4*)(bo + nt * 16 + quad * 4);
        f32x4 b4v; b4v[0] = b4.x; b4v[1] = b4.y; b4v[2] = b4.z; b4v[3] = b4.w;
        #pragma unroll
        for (int mt = 0; mt < 2; ++mt) {
            f32x4 v = acc[mt][nt] + b4v;
            *(f32x4*)&out[((size_t)bl * 256 + rowloc + mt * 16 + n16) * 64
                          + nt * 16 + quad * 4] = v;
        }
    }
}

extern "C" void kernel_launch(void* const* d_in, const int* in_sizes, int n_in,
                              void* d_out, int out_size, void* d_ws, size_t ws_size,
                              hipStream_t stream) {
    const float* z  = (const float*)d_in[0];
    const float* ls = (const float*)d_in[1];
    const float* lb = (const float*)d_in[2];
    const float* Wq = (const float*)d_in[3];
    const float* Wk = (const float*)d_in[4];
    const float* Wv = (const float*)d_in[5];
    const float* Wg = (const float*)d_in[6];
    const float* bg = (const float*)d_in[7];
    const float* Wo = (const float*)d_in[8];
    const float* bo = (const float*)d_in[9];
    float* out = (float*)d_out;
    short* wsp = (short*)d_ws;

    hipLaunchKernelGGL(ka_fused, dim3(2048), dim3(256), 0, stream,
                       z, ls, lb, Wq, Wk, Wv, Wg, bg, wsp);
    hipLaunchKernelGGL(k3_out, dim3(1024), dim3(256), 0, stream, wsp, Wo, bo, out);
}